// Round 1
// 348.308 us; speedup vs baseline: 1.0796x; 1.0796x over previous
//
#include <hip/hip_runtime.h>

typedef __bf16 bf16;
typedef __attribute__((ext_vector_type(8))) __bf16 bf16x8;
typedef __attribute__((ext_vector_type(4))) __bf16 bf16x4;
typedef __attribute__((ext_vector_type(4))) float f32x4;

#define B_ 4
#define T_ 2048
#define E_ 1024
#define H_ 16
#define KV_ 4
#define D_ 64
#define KVD_ 256
#define KVSTRIDE_ 512
#define M_ 8192

#define MASK_NEG (-3.0e4f)  // finite sentinel: exp args stay bounded

// ---- 8-element loads -> bf16x8 fragment, overloaded on source dtype ----
__device__ inline bf16x8 load8(const bf16* p) { return *(const bf16x8*)p; }
__device__ inline bf16x8 load8(const float* p) {
  f32x4 a = *(const f32x4*)p;
  f32x4 b = *(const f32x4*)(p + 4);
  bf16x8 r;
#pragma unroll
  for (int j = 0; j < 4; ++j) { r[j] = (bf16)a[j]; r[4 + j] = (bf16)b[j]; }
  return r;
}

// async global->LDS, 16B per lane; LDS dest is wave-uniform base + lane*16
__device__ inline void gload_lds16(const bf16* g, bf16* l) {
  __builtin_amdgcn_global_load_lds(
      (const __attribute__((address_space(1))) void*)g,
      (__attribute__((address_space(3))) void*)l, 16, 0, 0);
}

// ---------------- cast: fp32 -> bf16, 8 elems/thread ----------------
__global__ __launch_bounds__(256) void cast_k(const float* __restrict__ src,
                                              bf16* __restrict__ dst) {
  size_t i = ((size_t)blockIdx.x * 256 + threadIdx.x) * 8;
  *(bf16x8*)(dst + i) = load8(src + i);
}

// ---------------- transpose+cast: WT[n][k] = bf16(W[k][n]), W is fp32 ----------------
__global__ __launch_bounds__(256) void transpose_k(const float* __restrict__ W,
                                                   bf16* __restrict__ WT,
                                                   int K, int N) {
  __shared__ bf16 tile[32][33];
  int k0 = blockIdx.x * 32, n0 = blockIdx.y * 32;
  int tr = threadIdx.x >> 5;  // 0..7
  int tc = threadIdx.x & 31;
#pragma unroll
  for (int i = 0; i < 32; i += 8)
    tile[tr + i][tc] = (bf16)W[(size_t)(k0 + tr + i) * N + n0 + tc];
  __syncthreads();
#pragma unroll
  for (int i = 0; i < 32; i += 8)
    WT[(size_t)(n0 + tr + i) * K + k0 + tc] = tile[tc][tr + i];
}

// ---------------- V head-transpose: VbT[b][kv][d][t] = KVb[b*T+t][256 + kv*64+d] ----------------
__global__ __launch_bounds__(256) void vtrans_k(const bf16* __restrict__ src,
                                                bf16* __restrict__ dst) {
  __shared__ bf16 tile[32][33];
  int r0 = blockIdx.x * 32;  // row in [8192) = b*T + t
  int c0 = blockIdx.y * 32;  // col in [256)  = kv*64 + d
  int tr = threadIdx.x >> 5, tc = threadIdx.x & 31;
#pragma unroll
  for (int i = 0; i < 32; i += 8)
    tile[tr + i][tc] = src[(size_t)(r0 + tr + i) * KVSTRIDE_ + 256 + c0 + tc];
  __syncthreads();
#pragma unroll
  for (int i = 0; i < 32; i += 8) {
    int c = c0 + tr + i;
    int r = r0 + tc;
    dst[(size_t)((r >> 11) * KVD_ + c) * T_ + (r & (T_ - 1))] = tile[tc][tr + i];
  }
}

// ---------------- GEMM (m97 structure): C = (A @ WT^T + bias) * scale ----------------
// A [M,K] bf16 row-major; WT [N,K] bf16 row-major; C [M,N].
// 128x128 tile, BK=32, 256 threads = 4 waves (2x2), global_load_lds width-16
// staging into linear LDS, 2-barrier K-loop, 16 MFMA/wave/K-step.
// bias split: col<nsplit -> bias0[col], else bias1[col-nsplit] (for fused KV).
template <typename CT>
__global__ __launch_bounds__(256) void gemm128_k(const bf16* __restrict__ A,
                                                 const bf16* __restrict__ WT,
                                                 const float* __restrict__ bias0,
                                                 const float* __restrict__ bias1,
                                                 int nsplit,
                                                 CT* __restrict__ C,
                                                 int M, int N, int K, float scale) {
  const int m0 = blockIdx.x * 128;
  const int n0 = blockIdx.y * 128;
  const int tid = threadIdx.x;
  const int wave = tid >> 6;
  const int lane = tid & 63;
  const int wr = wave >> 1;  // wave row (0/1) -> 64 M-rows
  const int wc = wave & 1;   // wave col (0/1) -> 64 N-cols
  const int fr = lane & 15;
  const int quad = lane >> 4;

  __shared__ bf16 sA[128][32];  // 8 KB, linear: row stride 64 B
  __shared__ bf16 sB[128][32];  // 8 KB

  f32x4 acc[4][4] = {};

  // staging map: call cc = wave*2 + c covers rows cc*16..cc*16+15 (16 rows x 64 B = 1 KB
  // = 64 lanes x 16 B). lane -> row = lane>>2, k-chunk = (lane&3)*8.
  const int ldr = lane >> 2;
  const int ldk = (lane & 3) * 8;
  const bf16* Ag0 = A + (size_t)(m0 + wave * 32 + ldr) * K + ldk;
  const bf16* Ag1 = Ag0 + (size_t)16 * K;
  const bf16* Bg0 = WT + (size_t)(n0 + wave * 32 + ldr) * K + ldk;
  const bf16* Bg1 = Bg0 + (size_t)16 * K;
  bf16* sA0 = &sA[wave * 32][0];       // wave-uniform LDS bases
  bf16* sA1 = &sA[wave * 32 + 16][0];
  bf16* sB0 = &sB[wave * 32][0];
  bf16* sB1 = &sB[wave * 32 + 16][0];

  for (int k0 = 0; k0 < K; k0 += 32) {
    gload_lds16(Ag0 + k0, sA0);
    gload_lds16(Ag1 + k0, sA1);
    gload_lds16(Bg0 + k0, sB0);
    gload_lds16(Bg1 + k0, sB1);
    __syncthreads();  // vmcnt(0) drain emitted by compiler before barrier

    bf16x8 af[4], bfr[4];
#pragma unroll
    for (int m = 0; m < 4; ++m)
      af[m] = *(const bf16x8*)(&sA[wr * 64 + m * 16 + fr][quad * 8]);
#pragma unroll
    for (int n = 0; n < 4; ++n)
      bfr[n] = *(const bf16x8*)(&sB[wc * 64 + n * 16 + fr][quad * 8]);
#pragma unroll
    for (int m = 0; m < 4; ++m)
#pragma unroll
      for (int n = 0; n < 4; ++n)
        acc[m][n] = __builtin_amdgcn_mfma_f32_16x16x32_bf16(af[m], bfr[n], acc[m][n], 0, 0, 0);
    __syncthreads();  // frag reads done before next iter's staging overwrites
  }

#pragma unroll
  for (int n = 0; n < 4; ++n) {
    int col = n0 + wc * 64 + n * 16 + fr;
    float bv = (col < nsplit) ? bias0[col] : bias1[col - nsplit];
#pragma unroll
    for (int m = 0; m < 4; ++m) {
#pragma unroll
      for (int i = 0; i < 4; ++i) {
        int row = m0 + wr * 64 + m * 16 + quad * 4 + i;
        C[(size_t)row * N + col] = (CT)((acc[m][n][i] + bv) * scale);
      }
    }
  }
}

// ---------------- MFMA flash attention, butterfly-balanced (unchanged core) ----------------
// Grid (16, 16, 4) = (pair, head, batch); 256 threads = 4 waves.
// K rows read from fused KV buffer with stride 512 (cols 0..255).
__global__ __launch_bounds__(256) void attn_k(const bf16* __restrict__ Qg,
                                              const bf16* __restrict__ Kg,
                                              const bf16* __restrict__ VTg,
                                              bf16* __restrict__ Og) {
  const int jp = blockIdx.x;  // pair index 0..15
  const int h = blockIdx.y;
  const int b = blockIdx.z;
  const int kv = h >> 2;  // G = 4
  const int tid = threadIdx.x;
  const int wave = tid >> 6;
  const int lane = tid & 63;
  const int fr = lane & 15;
  const int quad = lane >> 4;

  __shared__ bf16 Ks[64][72];  // [key][d]   9216 B
  __shared__ bf16 Vt[64][72];  // [d][key]   9216 B
  __shared__ bf16 Ps[64][72];  // [q][key]   9216 B -> 27648 total (5 blocks/CU)

  // staging maps
  const int skey = tid & 63;        // K: key row
  const int sdc = (tid >> 6) * 16;  // K: dim seg
  const int svd = tid >> 2;         // V: d row 0..63
  const int svk = (tid & 3) * 16;   // V: key seg
  const bf16* kbase = Kg + (size_t)(b * T_ + skey) * KVSTRIDE_ + kv * 64 + sdc;
  const bf16* vbase = VTg + (size_t)((b * KV_ + kv) * D_ + svd) * T_ + svk;

  for (int ph = 0; ph < 2; ++ph) {
    const int qb = ph ? (31 - jp) : jp;

    // Q A-fragments for this phase. m=fr -> q row qb*64+wave*16+fr.
    bf16x8 qa0, qa1;
    {
      const bf16* qsrc = Qg + (size_t)(b * T_ + qb * 64 + wave * 16 + fr) * E_ + h * 64 + quad * 8;
      qa0 = *(const bf16x8*)(qsrc);
      qa1 = *(const bf16x8*)(qsrc + 32);
    }

    f32x4 Oacc[4] = {};  // C-layout: row quad*4+i, col dt*16+fr
    float m_run[4], l_run[4];
#pragma unroll
    for (int i = 0; i < 4; ++i) { m_run[i] = MASK_NEG; l_run[i] = 0.f; }

    bf16x8 k0p, k1p, v0p, v1p;  // prefetch registers (static names)
    k0p = *(const bf16x8*)(kbase);
    k1p = *(const bf16x8*)(kbase + 8);
    v0p = *(const bf16x8*)(vbase);
    v1p = *(const bf16x8*)(vbase + 8);

    for (int kb = 0; kb <= qb; ++kb) {
      // ---- staged regs -> LDS (vmcnt of prefetch drains here) ----
      *(bf16x8*)(&Ks[skey][sdc]) = k0p;
      *(bf16x8*)(&Ks[skey][sdc + 8]) = k1p;
      *(bf16x8*)(&Vt[svd][svk]) = v0p;
      *(bf16x8*)(&Vt[svd][svk + 8]) = v1p;
      __syncthreads();

      if (kb < qb) {  // prefetch next tile; latency hidden behind compute
        const bf16* kp = kbase + (size_t)(kb + 1) * 64 * KVSTRIDE_;
        const bf16* vp = vbase + (size_t)(kb + 1) * 64;
        k0p = *(const bf16x8*)(kp);
        k1p = *(const bf16x8*)(kp + 8);
        v0p = *(const bf16x8*)(vp);
        v1p = *(const bf16x8*)(vp + 8);
      } else if (ph == 0) {  // prime next phase's tile 0 (L2-hot)
        k0p = *(const bf16x8*)(kbase);
        k1p = *(const bf16x8*)(kbase + 8);
        v0p = *(const bf16x8*)(vbase);
        v1p = *(const bf16x8*)(vbase + 8);
      }

      // ---- QK^T: S[m=q][n=key], B[k=d][n=key] = Ks[n][k] (row-major b128) ----
      f32x4 S[4] = {};
#pragma unroll
      for (int nt = 0; nt < 4; ++nt) {
        bf16x8 kf0 = *(const bf16x8*)(&Ks[nt * 16 + fr][quad * 8]);
        bf16x8 kf1 = *(const bf16x8*)(&Ks[nt * 16 + fr][32 + quad * 8]);
        S[nt] = __builtin_amdgcn_mfma_f32_16x16x32_bf16(qa0, kf0, S[nt], 0, 0, 0);
        S[nt] = __builtin_amdgcn_mfma_f32_16x16x32_bf16(qa1, kf1, S[nt], 0, 0, 0);
      }

      if (kb == qb) {  // causal mask, diagonal block only
#pragma unroll
        for (int nt = 0; nt < 4; ++nt) {
          int colk = nt * 16 + fr;
#pragma unroll
          for (int i = 0; i < 4; ++i) {
            int rowq = wave * 16 + quad * 4 + i;
            if (colk > rowq) S[nt][i] = MASK_NEG;
          }
        }
      }

      // ---- online softmax; rows quad*4+i, reduce over the 16 fr-lanes ----
#pragma unroll
      for (int i = 0; i < 4; ++i) {
        float mb = fmaxf(fmaxf(S[0][i], S[1][i]), fmaxf(S[2][i], S[3][i]));
        mb = fmaxf(mb, __shfl_xor(mb, 1, 64));
        mb = fmaxf(mb, __shfl_xor(mb, 2, 64));
        mb = fmaxf(mb, __shfl_xor(mb, 4, 64));
        mb = fmaxf(mb, __shfl_xor(mb, 8, 64));
        float mn = fmaxf(m_run[i], mb);
        float al = __expf(m_run[i] - mn);
        m_run[i] = mn;
        float ps = 0.f;
#pragma unroll
        for (int nt = 0; nt < 4; ++nt) {
          float p = __expf(S[nt][i] - mn);  // arg <= 0
          S[nt][i] = p;
          ps += p;
        }
        ps += __shfl_xor(ps, 1, 64);
        ps += __shfl_xor(ps, 2, 64);
        ps += __shfl_xor(ps, 4, 64);
        ps += __shfl_xor(ps, 8, 64);
        l_run[i] = l_run[i] * al + ps;
#pragma unroll
        for (int dt = 0; dt < 4; ++dt) Oacc[dt][i] *= al;
      }

      // ---- P (C-layout) -> LDS; wave-local rows, no cross-wave barrier ----
#pragma unroll
      for (int nt = 0; nt < 4; ++nt)
#pragma unroll
        for (int i = 0; i < 4; ++i)
          Ps[wave * 16 + quad * 4 + i][nt * 16 + fr] = (bf16)S[nt][i];
      __threadfence_block();  // drain ds_write before same-wave ds_read

      // ---- PV: A = P rows of this wave; B[k=key][n=d] = Vt[n][k] ----
      bf16x8 pa0 = *(const bf16x8*)(&Ps[wave * 16 + fr][quad * 8]);
      bf16x8 pa1 = *(const bf16x8*)(&Ps[wave * 16 + fr][32 + quad * 8]);
#pragma unroll
      for (int dt = 0; dt < 4; ++dt) {
        bf16x8 vf0 = *(const bf16x8*)(&Vt[dt * 16 + fr][quad * 8]);
        bf16x8 vf1 = *(const bf16x8*)(&Vt[dt * 16 + fr][32 + quad * 8]);
        Oacc[dt] = __builtin_amdgcn_mfma_f32_16x16x32_bf16(pa0, vf0, Oacc[dt], 0, 0, 0);
        Oacc[dt] = __builtin_amdgcn_mfma_f32_16x16x32_bf16(pa1, vf1, Oacc[dt], 0, 0, 0);
      }
      __syncthreads();  // all LDS reads done before next iter's staging writes
    }

    // ---- epilogue for this phase: O /= l, write bf16 ----
#pragma unroll
    for (int i = 0; i < 4; ++i) {
      float inv = 1.f / fmaxf(l_run[i], 1e-30f);
      bf16* dst = Og + (size_t)(b * T_ + qb * 64 + wave * 16 + quad * 4 + i) * E_ + h * 64;
#pragma unroll
      for (int dt = 0; dt < 4; ++dt)
        dst[dt * 16 + fr] = (bf16)(Oacc[dt][i] * inv);
    }
  }
}

extern "C" void kernel_launch(void* const* d_in, const int* in_sizes, int n_in,
                              void* d_out, int out_size, void* d_ws, size_t ws_size,
                              hipStream_t stream) {
  (void)in_sizes; (void)n_in; (void)out_size; (void)ws_size;
  // Reference dtypes are float32 for ALL inputs and the output.
  const float* hidden = (const float*)d_in[0];
  // d_in[1] = attention_mask: deterministically causal -> applied analytically
  const float* Wq = (const float*)d_in[2];
  const float* bq = (const float*)d_in[3];
  const float* Wk = (const float*)d_in[4];
  const float* bk = (const float*)d_in[5];
  const float* Wv = (const float*)d_in[6];
  const float* bv = (const float*)d_in[7];
  const float* Wo = (const float*)d_in[8];
  const float* bo = (const float*)d_in[9];
  float* out = (float*)d_out;

  char* ws = (char*)d_ws;
  bf16* WqT  = (bf16*)(ws);                  // [0, 2 MB)
  bf16* WoT  = (bf16*)(ws + (2u << 20));     // [2, 4 MB)
  bf16* WkvT = (bf16*)(ws + (4u << 20));     // [4, 5 MB)  512x1024 bf16
  bf16* Qb   = (bf16*)(ws + (5u << 20));     // [5, 21 MB)
  bf16* KVb  = (bf16*)(ws + (21u << 20));    // [21, 29 MB) 8192x512: cols 0-255 K, 256-511 V
  // Hb (bf16 hidden) aliases Ab: Hb used only before attn_k, Ab only from attn_k on.
  bf16* Hb   = (bf16*)(ws + (29u << 20));    // [29, 45 MB)
  bf16* Ab   = (bf16*)(ws + (29u << 20));
  bf16* VbT  = (bf16*)(ws + (45u << 20));    // [45, 49 MB)

  cast_k<<<dim3(M_ * E_ / (256 * 8)), 256, 0, stream>>>(hidden, Hb);
  transpose_k<<<dim3(32, 32), 256, 0, stream>>>(Wq, WqT, 1024, 1024);
  transpose_k<<<dim3(32, 8), 256, 0, stream>>>(Wk, WkvT, 1024, 256);
  transpose_k<<<dim3(32, 8), 256, 0, stream>>>(Wv, WkvT + (256u * 1024u), 1024, 256);
  transpose_k<<<dim3(32, 32), 256, 0, stream>>>(Wo, WoT, 1024, 1024);

  // q = (x@Wq + bq) * D^-0.5 ; fused kv = x@[Wk|Wv] + [bk|bv]
  gemm128_k<bf16><<<dim3(64, 8), 256, 0, stream>>>(Hb, WqT, bq, bq, 1 << 30, Qb, M_, E_, E_, 0.125f);
  gemm128_k<bf16><<<dim3(64, 4), 256, 0, stream>>>(Hb, WkvT, bk, bv, 256, KVb, M_, KVSTRIDE_, E_, 1.0f);

  vtrans_k<<<dim3(256, 8), 256, 0, stream>>>(KVb, VbT);

  attn_k<<<dim3(16, 16, 4), 256, 0, stream>>>(Qb, KVb, VbT, Ab);

  gemm128_k<float><<<dim3(64, 8), 256, 0, stream>>>(Ab, WoT, bo, bo, 1 << 30, out, M_, E_, E_, 1.0f);
}

// Round 2
// 313.679 us; speedup vs baseline: 1.1987x; 1.1104x over previous
//
#include <hip/hip_runtime.h>

typedef __bf16 bf16;
typedef __attribute__((ext_vector_type(8))) __bf16 bf16x8;
typedef __attribute__((ext_vector_type(4))) __bf16 bf16x4;
typedef __attribute__((ext_vector_type(4))) float f32x4;

#define B_ 4
#define T_ 2048
#define E_ 1024
#define H_ 16
#define KV_ 4
#define D_ 64
#define KVD_ 256
#define KVSTRIDE_ 512
#define M_ 8192

#define MASK_NEG (-3.0e4f)  // finite sentinel: exp2 args stay bounded

// ---- 8-element loads -> bf16x8 fragment, overloaded on source dtype ----
__device__ inline bf16x8 load8(const bf16* p) { return *(const bf16x8*)p; }
__device__ inline bf16x8 load8(const float* p) {
  f32x4 a = *(const f32x4*)p;
  f32x4 b = *(const f32x4*)(p + 4);
  bf16x8 r;
#pragma unroll
  for (int j = 0; j < 4; ++j) { r[j] = (bf16)a[j]; r[4 + j] = (bf16)b[j]; }
  return r;
}

// async global->LDS, 16B per lane; LDS dest is wave-uniform base + lane*16
__device__ inline void gload_lds16(const bf16* g, bf16* l) {
  __builtin_amdgcn_global_load_lds(
      (const __attribute__((address_space(1))) void*)g,
      (__attribute__((address_space(3))) void*)l, 16, 0, 0);
}

// ---------------- cast: fp32 -> bf16, 8 elems/thread ----------------
__global__ __launch_bounds__(256) void cast_k(const float* __restrict__ src,
                                              bf16* __restrict__ dst) {
  size_t i = ((size_t)blockIdx.x * 256 + threadIdx.x) * 8;
  *(bf16x8*)(dst + i) = load8(src + i);
}

// ---------------- transpose+cast: WT[n][k] = bf16(W[k][n]), W is fp32 ----------------
__global__ __launch_bounds__(256) void transpose_k(const float* __restrict__ W,
                                                   bf16* __restrict__ WT,
                                                   int K, int N) {
  __shared__ bf16 tile[32][33];
  int k0 = blockIdx.x * 32, n0 = blockIdx.y * 32;
  int tr = threadIdx.x >> 5;  // 0..7
  int tc = threadIdx.x & 31;
#pragma unroll
  for (int i = 0; i < 32; i += 8)
    tile[tr + i][tc] = (bf16)W[(size_t)(k0 + tr + i) * N + n0 + tc];
  __syncthreads();
#pragma unroll
  for (int i = 0; i < 32; i += 8)
    WT[(size_t)(n0 + tr + i) * K + k0 + tc] = tile[tc][tr + i];
}

// ---------------- V head-transpose: VbT[b][kv][d][t] = KVb[b*T+t][256 + kv*64+d] ----------------
__global__ __launch_bounds__(256) void vtrans_k(const bf16* __restrict__ src,
                                                bf16* __restrict__ dst) {
  __shared__ bf16 tile[32][33];
  int r0 = blockIdx.x * 32;  // row in [8192) = b*T + t
  int c0 = blockIdx.y * 32;  // col in [256)  = kv*64 + d
  int tr = threadIdx.x >> 5, tc = threadIdx.x & 31;
#pragma unroll
  for (int i = 0; i < 32; i += 8)
    tile[tr + i][tc] = src[(size_t)(r0 + tr + i) * KVSTRIDE_ + 256 + c0 + tc];
  __syncthreads();
#pragma unroll
  for (int i = 0; i < 32; i += 8) {
    int c = c0 + tr + i;
    int r = r0 + tc;
    dst[(size_t)((r >> 11) * KVD_ + c) * T_ + (r & (T_ - 1))] = tile[tc][tr + i];
  }
}

// ---------------- GEMM (m97 structure): C = (A @ WT^T + bias) * scale ----------------
// A [M,K] bf16 row-major; WT [N,K] bf16 row-major; C [M,N].
// 128x128 tile, BK=32, 256 threads = 4 waves (2x2), global_load_lds width-16
// staging into linear LDS, 2-barrier K-loop, 16 MFMA/wave/K-step.
// bias split: col<nsplit -> bias0[col], else bias1[col-nsplit] (for fused KV).
template <typename CT>
__global__ __launch_bounds__(256) void gemm128_k(const bf16* __restrict__ A,
                                                 const bf16* __restrict__ WT,
                                                 const float* __restrict__ bias0,
                                                 const float* __restrict__ bias1,
                                                 int nsplit,
                                                 CT* __restrict__ C,
                                                 int M, int N, int K, float scale) {
  const int m0 = blockIdx.x * 128;
  const int n0 = blockIdx.y * 128;
  const int tid = threadIdx.x;
  const int wave = tid >> 6;
  const int lane = tid & 63;
  const int wr = wave >> 1;  // wave row (0/1) -> 64 M-rows
  const int wc = wave & 1;   // wave col (0/1) -> 64 N-cols
  const int fr = lane & 15;
  const int quad = lane >> 4;

  __shared__ bf16 sA[128][32];  // 8 KB, linear: row stride 64 B
  __shared__ bf16 sB[128][32];  // 8 KB

  f32x4 acc[4][4] = {};

  const int ldr = lane >> 2;
  const int ldk = (lane & 3) * 8;
  const bf16* Ag0 = A + (size_t)(m0 + wave * 32 + ldr) * K + ldk;
  const bf16* Ag1 = Ag0 + (size_t)16 * K;
  const bf16* Bg0 = WT + (size_t)(n0 + wave * 32 + ldr) * K + ldk;
  const bf16* Bg1 = Bg0 + (size_t)16 * K;
  bf16* sA0 = &sA[wave * 32][0];       // wave-uniform LDS bases
  bf16* sA1 = &sA[wave * 32 + 16][0];
  bf16* sB0 = &sB[wave * 32][0];
  bf16* sB1 = &sB[wave * 32 + 16][0];

  for (int k0 = 0; k0 < K; k0 += 32) {
    gload_lds16(Ag0 + k0, sA0);
    gload_lds16(Ag1 + k0, sA1);
    gload_lds16(Bg0 + k0, sB0);
    gload_lds16(Bg1 + k0, sB1);
    __syncthreads();  // vmcnt(0) drain emitted by compiler before barrier

    bf16x8 af[4], bfr[4];
#pragma unroll
    for (int m = 0; m < 4; ++m)
      af[m] = *(const bf16x8*)(&sA[wr * 64 + m * 16 + fr][quad * 8]);
#pragma unroll
    for (int n = 0; n < 4; ++n)
      bfr[n] = *(const bf16x8*)(&sB[wc * 64 + n * 16 + fr][quad * 8]);
#pragma unroll
    for (int m = 0; m < 4; ++m)
#pragma unroll
      for (int n = 0; n < 4; ++n)
        acc[m][n] = __builtin_amdgcn_mfma_f32_16x16x32_bf16(af[m], bfr[n], acc[m][n], 0, 0, 0);
    __syncthreads();  // frag reads done before next iter's staging overwrites
  }

#pragma unroll
  for (int n = 0; n < 4; ++n) {
    int col = n0 + wc * 64 + n * 16 + fr;
    float bv = (col < nsplit) ? bias0[col] : bias1[col - nsplit];
#pragma unroll
    for (int m = 0; m < 4; ++m) {
#pragma unroll
      for (int i = 0; i < 4; ++i) {
        int row = m0 + wr * 64 + m * 16 + quad * 4 + i;
        C[(size_t)row * N + col] = (CT)((acc[m][n][i] + bv) * scale);
      }
    }
  }
}

// ---------------- MFMA flash attention, swapped-operand (S^T / O^T) ----------------
// Grid (16, 16, 4) = (pair, head, batch); 256 threads = 4 waves; butterfly pairing.
// QK^T computed as S^T = mfma(K_frag, Q_frag): SAME LDS reads / Q regs as before,
// but each lane's C-fragment now holds one q (col = lane&15) x 16 keys.
//  -> softmax reduce: in-lane + 2 shuffles (was 32 shuffles)
//  -> scalar m/l state, 1 rescale-exp (was 4), exact defer branch on max growth
//  -> P^T round-trip: 4x ds_write_b64 + 2x ds_read_b128 (was 16x ds_write_b16)
//  -> PV swapped: O^T = mfma(V^T_frag, P^T_frag); epilogue packs bf16x4 stores.
// exp uses exp2; log2(e) is folded into the Q projection scale.
__global__ __launch_bounds__(256) void attn_k(const bf16* __restrict__ Qg,
                                              const bf16* __restrict__ Kg,
                                              const bf16* __restrict__ VTg,
                                              bf16* __restrict__ Og) {
  const int jp = blockIdx.x;  // pair index 0..15
  const int h = blockIdx.y;
  const int b = blockIdx.z;
  const int kv = h >> 2;  // G = 4
  const int tid = threadIdx.x;
  const int wave = tid >> 6;
  const int lane = tid & 63;
  const int fr = lane & 15;   // q (col) index within the wave's 16 q-rows
  const int quad = lane >> 4;

  __shared__ bf16 Ks[64][72];  // [key][d]     9216 B
  __shared__ bf16 Vt[64][72];  // [d][key]     9216 B
  __shared__ bf16 Pt[64][72];  // [q][key] P^T 9216 B -> 27648 total (5 blocks/CU)

  // staging maps
  const int skey = tid & 63;        // K: key row
  const int sdc = (tid >> 6) * 16;  // K: dim seg
  const int svd = tid >> 2;         // V: d row 0..63
  const int svk = (tid & 3) * 16;   // V: key seg
  const bf16* kbase = Kg + (size_t)(b * T_ + skey) * KVSTRIDE_ + kv * 64 + sdc;
  const bf16* vbase = VTg + (size_t)((b * KV_ + kv) * D_ + svd) * T_ + svk;

  for (int ph = 0; ph < 2; ++ph) {
    const int qb = ph ? (31 - jp) : jp;

    // Q fragments: B-operand layout == A-operand layout (col=fr, k=d=quad*8+j).
    bf16x8 qa0, qa1;
    {
      const bf16* qsrc = Qg + (size_t)(b * T_ + qb * 64 + wave * 16 + fr) * E_ + h * 64 + quad * 8;
      qa0 = *(const bf16x8*)(qsrc);
      qa1 = *(const bf16x8*)(qsrc + 32);
    }

    f32x4 Oacc[4] = {};  // O^T: row d = dt*16+quad*4+i, col q = fr
    float m_run = MASK_NEG, l_run = 0.f;

    bf16x8 k0p, k1p, v0p, v1p;  // prefetch registers (static names)
    k0p = *(const bf16x8*)(kbase);
    k1p = *(const bf16x8*)(kbase + 8);
    v0p = *(const bf16x8*)(vbase);
    v1p = *(const bf16x8*)(vbase + 8);

    for (int kb = 0; kb <= qb; ++kb) {
      // ---- staged regs -> LDS (vmcnt of prefetch drains here) ----
      *(bf16x8*)(&Ks[skey][sdc]) = k0p;
      *(bf16x8*)(&Ks[skey][sdc + 8]) = k1p;
      *(bf16x8*)(&Vt[svd][svk]) = v0p;
      *(bf16x8*)(&Vt[svd][svk + 8]) = v1p;
      __syncthreads();

      if (kb < qb) {  // prefetch next tile; latency hidden behind compute
        const bf16* kp = kbase + (size_t)(kb + 1) * 64 * KVSTRIDE_;
        const bf16* vp = vbase + (size_t)(kb + 1) * 64;
        k0p = *(const bf16x8*)(kp);
        k1p = *(const bf16x8*)(kp + 8);
        v0p = *(const bf16x8*)(vp);
        v1p = *(const bf16x8*)(vp + 8);
      } else if (ph == 0) {  // prime next phase's tile 0 (L2-hot)
        k0p = *(const bf16x8*)(kbase);
        k1p = *(const bf16x8*)(kbase + 8);
        v0p = *(const bf16x8*)(vbase);
        v1p = *(const bf16x8*)(vbase + 8);
      }

      // ---- S^T = K·Q^T: A = K[key][d] (same kf reads), B = Q (same regs) ----
      // C: S^T[key = nt*16 + quad*4 + i][q = fr]
      f32x4 S[4] = {};
#pragma unroll
      for (int nt = 0; nt < 4; ++nt) {
        bf16x8 kf0 = *(const bf16x8*)(&Ks[nt * 16 + fr][quad * 8]);
        bf16x8 kf1 = *(const bf16x8*)(&Ks[nt * 16 + fr][32 + quad * 8]);
        S[nt] = __builtin_amdgcn_mfma_f32_16x16x32_bf16(kf0, qa0, S[nt], 0, 0, 0);
        S[nt] = __builtin_amdgcn_mfma_f32_16x16x32_bf16(kf1, qa1, S[nt], 0, 0, 0);
      }

      if (kb == qb) {  // causal mask, diagonal block only: key_local > q_local
        const int ql = wave * 16 + fr;
#pragma unroll
        for (int nt = 0; nt < 4; ++nt)
#pragma unroll
          for (int i = 0; i < 4; ++i)
            if (nt * 16 + quad * 4 + i > ql) S[nt][i] = MASK_NEG;
      }

      // ---- online softmax (base-2 domain); one q per lane ----
      float pm = S[0][0];
#pragma unroll
      for (int nt = 0; nt < 4; ++nt)
#pragma unroll
        for (int i = 0; i < 4; ++i) pm = fmaxf(pm, S[nt][i]);
      pm = fmaxf(pm, __shfl_xor(pm, 16, 64));
      pm = fmaxf(pm, __shfl_xor(pm, 32, 64));
      if (pm > m_run) {  // exact defer: skip O-rescale when max doesn't grow
        float al = exp2f(m_run - pm);
        m_run = pm;
        l_run *= al;
#pragma unroll
        for (int dt = 0; dt < 4; ++dt)
#pragma unroll
          for (int i = 0; i < 4; ++i) Oacc[dt][i] *= al;
      }
      float ps = 0.f;
#pragma unroll
      for (int nt = 0; nt < 4; ++nt)
#pragma unroll
        for (int i = 0; i < 4; ++i) {
          float p = exp2f(S[nt][i] - m_run);  // arg <= 0
          S[nt][i] = p;
          ps += p;
        }
      ps += __shfl_xor(ps, 16, 64);
      ps += __shfl_xor(ps, 32, 64);
      l_run += ps;

      // ---- P^T -> LDS: lane's 4 keys per nt are contiguous -> b64 writes ----
#pragma unroll
      for (int nt = 0; nt < 4; ++nt) {
        bf16x4 w;
#pragma unroll
        for (int i = 0; i < 4; ++i) w[i] = (bf16)S[nt][i];
        *(bf16x4*)(&Pt[wave * 16 + fr][nt * 16 + quad * 4]) = w;
      }
      __threadfence_block();  // drain ds_write before same-wave ds_read

      // ---- O^T += V^T·P^T: A = V^T[d][key] (same vf reads), B = P^T[key][q] ----
      bf16x8 pb0 = *(const bf16x8*)(&Pt[wave * 16 + fr][quad * 8]);
      bf16x8 pb1 = *(const bf16x8*)(&Pt[wave * 16 + fr][32 + quad * 8]);
#pragma unroll
      for (int dt = 0; dt < 4; ++dt) {
        bf16x8 vf0 = *(const bf16x8*)(&Vt[dt * 16 + fr][quad * 8]);
        bf16x8 vf1 = *(const bf16x8*)(&Vt[dt * 16 + fr][32 + quad * 8]);
        Oacc[dt] = __builtin_amdgcn_mfma_f32_16x16x32_bf16(vf0, pb0, Oacc[dt], 0, 0, 0);
        Oacc[dt] = __builtin_amdgcn_mfma_f32_16x16x32_bf16(vf1, pb1, Oacc[dt], 0, 0, 0);
      }
      __syncthreads();  // all LDS reads done before next iter's staging writes
    }

    // ---- epilogue: O^T holds 16 d-values for q = fr; pack 4x b64 stores ----
    {
      float inv = 1.f / fmaxf(l_run, 1e-30f);
      bf16* dst = Og + (size_t)(b * T_ + qb * 64 + wave * 16 + fr) * E_ + h * 64;
#pragma unroll
      for (int dt = 0; dt < 4; ++dt) {
        bf16x4 o;
#pragma unroll
        for (int i = 0; i < 4; ++i) o[i] = (bf16)(Oacc[dt][i] * inv);
        *(bf16x4*)(dst + dt * 16 + quad * 4) = o;
      }
    }
  }
}

extern "C" void kernel_launch(void* const* d_in, const int* in_sizes, int n_in,
                              void* d_out, int out_size, void* d_ws, size_t ws_size,
                              hipStream_t stream) {
  (void)in_sizes; (void)n_in; (void)out_size; (void)ws_size;
  // Reference dtypes are float32 for ALL inputs and the output.
  const float* hidden = (const float*)d_in[0];
  // d_in[1] = attention_mask: deterministically causal -> applied analytically
  const float* Wq = (const float*)d_in[2];
  const float* bq = (const float*)d_in[3];
  const float* Wk = (const float*)d_in[4];
  const float* bk = (const float*)d_in[5];
  const float* Wv = (const float*)d_in[6];
  const float* bv = (const float*)d_in[7];
  const float* Wo = (const float*)d_in[8];
  const float* bo = (const float*)d_in[9];
  float* out = (float*)d_out;

  char* ws = (char*)d_ws;
  bf16* WqT  = (bf16*)(ws);                  // [0, 2 MB)
  bf16* WoT  = (bf16*)(ws + (2u << 20));     // [2, 4 MB)
  bf16* WkvT = (bf16*)(ws + (4u << 20));     // [4, 5 MB)  512x1024 bf16
  bf16* Qb   = (bf16*)(ws + (5u << 20));     // [5, 21 MB)
  bf16* KVb  = (bf16*)(ws + (21u << 20));    // [21, 29 MB) 8192x512: cols 0-255 K, 256-511 V
  // Hb (bf16 hidden) aliases Ab: Hb used only before attn_k, Ab only from attn_k on.
  bf16* Hb   = (bf16*)(ws + (29u << 20));    // [29, 45 MB)
  bf16* Ab   = (bf16*)(ws + (29u << 20));
  bf16* VbT  = (bf16*)(ws + (45u << 20));    // [45, 49 MB)

  cast_k<<<dim3(M_ * E_ / (256 * 8)), 256, 0, stream>>>(hidden, Hb);
  transpose_k<<<dim3(32, 32), 256, 0, stream>>>(Wq, WqT, 1024, 1024);
  transpose_k<<<dim3(32, 8), 256, 0, stream>>>(Wk, WkvT, 1024, 256);
  transpose_k<<<dim3(32, 8), 256, 0, stream>>>(Wv, WkvT + (256u * 1024u), 1024, 256);
  transpose_k<<<dim3(32, 32), 256, 0, stream>>>(Wo, WoT, 1024, 1024);

  // q = (x@Wq + bq) * D^-0.5 * log2(e)  (softmax runs in base-2 domain)
  gemm128_k<bf16><<<dim3(64, 8), 256, 0, stream>>>(Hb, WqT, bq, bq, 1 << 30, Qb, M_, E_, E_,
                                                   0.125f * 1.4426950408889634f);
  gemm128_k<bf16><<<dim3(64, 4), 256, 0, stream>>>(Hb, WkvT, bk, bv, 256, KVb, M_, KVSTRIDE_, E_, 1.0f);

  vtrans_k<<<dim3(256, 8), 256, 0, stream>>>(KVb, VbT);

  attn_k<<<dim3(16, 16, 4), 256, 0, stream>>>(Qb, KVb, VbT, Ab);

  gemm128_k<float><<<dim3(64, 8), 256, 0, stream>>>(Ab, WoT, bo, bo, 1 << 30, out, M_, E_, E_, 1.0f);
}

// Round 3
// 285.616 us; speedup vs baseline: 1.3165x; 1.0983x over previous
//
#include <hip/hip_runtime.h>

typedef __bf16 bf16;
typedef __attribute__((ext_vector_type(8))) __bf16 bf16x8;
typedef __attribute__((ext_vector_type(4))) __bf16 bf16x4;
typedef __attribute__((ext_vector_type(4))) float f32x4;

#define B_ 4
#define T_ 2048
#define E_ 1024
#define H_ 16
#define KV_ 4
#define D_ 64
#define KVD_ 256
#define QKVS_ 1536   // fused QKV row stride: [Q 0..1023 | K 1024..1279 | V 1280..1535]
#define M_ 8192

#define MASK_NEG (-3.0e4f)  // finite sentinel: exp2 args stay bounded
#define QSCALE (0.125f * 1.4426950408889634f)  // D^-0.5 * log2(e)

// ---- 8-element loads -> bf16x8 fragment, overloaded on source dtype ----
__device__ inline bf16x8 load8(const bf16* p) { return *(const bf16x8*)p; }
__device__ inline bf16x8 load8(const float* p) {
  f32x4 a = *(const f32x4*)p;
  f32x4 b = *(const f32x4*)(p + 4);
  bf16x8 r;
#pragma unroll
  for (int j = 0; j < 4; ++j) { r[j] = (bf16)a[j]; r[4 + j] = (bf16)b[j]; }
  return r;
}

// async global->LDS, 16B per lane; LDS dest is wave-uniform base + lane*16
__device__ inline void gload_lds16(const bf16* g, bf16* l) {
  __builtin_amdgcn_global_load_lds(
      (const __attribute__((address_space(1))) void*)g,
      (__attribute__((address_space(3))) void*)l, 16, 0, 0);
}

// ---------------- cast: fp32 -> bf16, 8 elems/thread ----------------
__global__ __launch_bounds__(256) void cast_k(const float* __restrict__ src,
                                              bf16* __restrict__ dst) {
  size_t i = ((size_t)blockIdx.x * 256 + threadIdx.x) * 8;
  *(bf16x8*)(dst + i) = load8(src + i);
}

// ---------------- merged weight prep: all 4 transposes in one launch ----------------
// z=0: Wq -> WqkvT rows 0..1023      (32x32 tile grid, y<32)
// z=1: Wo -> WoT                     (y<32)
// z=2: Wk -> WqkvT rows 1024..1279   (y<8)
// z=3: Wv -> WqkvT rows 1280..1535   (y<8)
__global__ __launch_bounds__(256) void wprep_k(const float* __restrict__ Wq,
                                               const float* __restrict__ Wk,
                                               const float* __restrict__ Wv,
                                               const float* __restrict__ Wo,
                                               bf16* __restrict__ WqkvT,
                                               bf16* __restrict__ WoT) {
  const int z = blockIdx.z;
  const float* W;
  bf16* WT;
  int N;
  if (z == 0) { W = Wq; WT = WqkvT; N = 1024; }
  else if (z == 1) { W = Wo; WT = WoT; N = 1024; }
  else if (z == 2) { if (blockIdx.y >= 8) return; W = Wk; WT = WqkvT + 1024 * 1024; N = 256; }
  else { if (blockIdx.y >= 8) return; W = Wv; WT = WqkvT + 1280 * 1024; N = 256; }

  __shared__ bf16 tile[32][33];
  int k0 = blockIdx.x * 32, n0 = blockIdx.y * 32;
  int tr = threadIdx.x >> 5;  // 0..7
  int tc = threadIdx.x & 31;
#pragma unroll
  for (int i = 0; i < 32; i += 8)
    tile[tr + i][tc] = (bf16)W[(size_t)(k0 + tr + i) * N + n0 + tc];
  __syncthreads();
#pragma unroll
  for (int i = 0; i < 32; i += 8)
    WT[(size_t)(n0 + tr + i) * 1024 + k0 + tc] = tile[tc][tr + i];
}

// ---------------- V head-transpose: VbT[b][kv][d][t] = QKV[b*T+t][1280 + kv*64+d] ----------------
__global__ __launch_bounds__(256) void vtrans_k(const bf16* __restrict__ src,
                                                bf16* __restrict__ dst) {
  __shared__ bf16 tile[32][33];
  int r0 = blockIdx.x * 32;  // row in [8192) = b*T + t
  int c0 = blockIdx.y * 32;  // col in [256)  = kv*64 + d
  int tr = threadIdx.x >> 5, tc = threadIdx.x & 31;
#pragma unroll
  for (int i = 0; i < 32; i += 8)
    tile[tr + i][tc] = src[(size_t)(r0 + tr + i) * QKVS_ + 1280 + c0 + tc];
  __syncthreads();
#pragma unroll
  for (int i = 0; i < 32; i += 8) {
    int c = c0 + tr + i;
    int r = r0 + tc;
    dst[(size_t)((r >> 11) * KVD_ + c) * T_ + (r & (T_ - 1))] = tile[tc][tr + i];
  }
}

// ---------------- fused QKV GEMM: QKV[r][c] = Hb @ [WqT;WkT;WvT]^T + bias, region scale ----------------
// 128x128 tile, BK=32, 256 threads = 4 waves (2x2), global_load_lds staging.
// Grid (64, 12) = 768 blocks = 3 blocks/CU.
__global__ __launch_bounds__(256) void qkv_gemm_k(const bf16* __restrict__ A,
                                                  const bf16* __restrict__ WT,
                                                  const float* __restrict__ bq,
                                                  const float* __restrict__ bk,
                                                  const float* __restrict__ bv,
                                                  bf16* __restrict__ C) {
  const int K = E_;
  const int m0 = blockIdx.x * 128;
  const int n0 = blockIdx.y * 128;
  const int tid = threadIdx.x;
  const int wave = tid >> 6;
  const int lane = tid & 63;
  const int wr = wave >> 1;
  const int wc = wave & 1;
  const int fr = lane & 15;
  const int quad = lane >> 4;

  __shared__ bf16 sA[128][32];
  __shared__ bf16 sB[128][32];

  f32x4 acc[4][4] = {};

  const int ldr = lane >> 2;
  const int ldk = (lane & 3) * 8;
  const bf16* Ag0 = A + (size_t)(m0 + wave * 32 + ldr) * K + ldk;
  const bf16* Ag1 = Ag0 + (size_t)16 * K;
  const bf16* Bg0 = WT + (size_t)(n0 + wave * 32 + ldr) * K + ldk;
  const bf16* Bg1 = Bg0 + (size_t)16 * K;
  bf16* sA0 = &sA[wave * 32][0];
  bf16* sA1 = &sA[wave * 32 + 16][0];
  bf16* sB0 = &sB[wave * 32][0];
  bf16* sB1 = &sB[wave * 32 + 16][0];

  for (int k0 = 0; k0 < K; k0 += 32) {
    gload_lds16(Ag0 + k0, sA0);
    gload_lds16(Ag1 + k0, sA1);
    gload_lds16(Bg0 + k0, sB0);
    gload_lds16(Bg1 + k0, sB1);
    __syncthreads();

    bf16x8 af[4], bfr[4];
#pragma unroll
    for (int m = 0; m < 4; ++m)
      af[m] = *(const bf16x8*)(&sA[wr * 64 + m * 16 + fr][quad * 8]);
#pragma unroll
    for (int n = 0; n < 4; ++n)
      bfr[n] = *(const bf16x8*)(&sB[wc * 64 + n * 16 + fr][quad * 8]);
#pragma unroll
    for (int m = 0; m < 4; ++m)
#pragma unroll
      for (int n = 0; n < 4; ++n)
        acc[m][n] = __builtin_amdgcn_mfma_f32_16x16x32_bf16(af[m], bfr[n], acc[m][n], 0, 0, 0);
    __syncthreads();
  }

#pragma unroll
  for (int n = 0; n < 4; ++n) {
    int col = n0 + wc * 64 + n * 16 + fr;
    // region select (uniform per 16-col segment): Q | K | V
    float bias, sc;
    if (col < 1024) { bias = bq[col]; sc = QSCALE; }
    else if (col < 1280) { bias = bk[col - 1024]; sc = 1.f; }
    else { bias = bv[col - 1280]; sc = 1.f; }
#pragma unroll
    for (int m = 0; m < 4; ++m) {
#pragma unroll
      for (int i = 0; i < 4; ++i) {
        int row = m0 + wr * 64 + m * 16 + quad * 4 + i;
        C[(size_t)row * QKVS_ + col] = (bf16)((acc[m][n][i] + bias) * sc);
      }
    }
  }
}

// ---------------- GEMM (m97 structure): C = A @ WT^T + bias (fp32 out) ----------------
__global__ __launch_bounds__(256) void gemm128_k(const bf16* __restrict__ A,
                                                 const bf16* __restrict__ WT,
                                                 const float* __restrict__ bias,
                                                 float* __restrict__ C,
                                                 int M, int N, int K) {
  const int m0 = blockIdx.x * 128;
  const int n0 = blockIdx.y * 128;
  const int tid = threadIdx.x;
  const int wave = tid >> 6;
  const int lane = tid & 63;
  const int wr = wave >> 1;
  const int wc = wave & 1;
  const int fr = lane & 15;
  const int quad = lane >> 4;

  __shared__ bf16 sA[128][32];
  __shared__ bf16 sB[128][32];

  f32x4 acc[4][4] = {};

  const int ldr = lane >> 2;
  const int ldk = (lane & 3) * 8;
  const bf16* Ag0 = A + (size_t)(m0 + wave * 32 + ldr) * K + ldk;
  const bf16* Ag1 = Ag0 + (size_t)16 * K;
  const bf16* Bg0 = WT + (size_t)(n0 + wave * 32 + ldr) * K + ldk;
  const bf16* Bg1 = Bg0 + (size_t)16 * K;
  bf16* sA0 = &sA[wave * 32][0];
  bf16* sA1 = &sA[wave * 32 + 16][0];
  bf16* sB0 = &sB[wave * 32][0];
  bf16* sB1 = &sB[wave * 32 + 16][0];

  for (int k0 = 0; k0 < K; k0 += 32) {
    gload_lds16(Ag0 + k0, sA0);
    gload_lds16(Ag1 + k0, sA1);
    gload_lds16(Bg0 + k0, sB0);
    gload_lds16(Bg1 + k0, sB1);
    __syncthreads();

    bf16x8 af[4], bfr[4];
#pragma unroll
    for (int m = 0; m < 4; ++m)
      af[m] = *(const bf16x8*)(&sA[wr * 64 + m * 16 + fr][quad * 8]);
#pragma unroll
    for (int n = 0; n < 4; ++n)
      bfr[n] = *(const bf16x8*)(&sB[wc * 64 + n * 16 + fr][quad * 8]);
#pragma unroll
    for (int m = 0; m < 4; ++m)
#pragma unroll
      for (int n = 0; n < 4; ++n)
        acc[m][n] = __builtin_amdgcn_mfma_f32_16x16x32_bf16(af[m], bfr[n], acc[m][n], 0, 0, 0);
    __syncthreads();
  }

#pragma unroll
  for (int n = 0; n < 4; ++n) {
    int col = n0 + wc * 64 + n * 16 + fr;
    float bv = bias[col];
#pragma unroll
    for (int m = 0; m < 4; ++m) {
#pragma unroll
      for (int i = 0; i < 4; ++i) {
        int row = m0 + wr * 64 + m * 16 + quad * 4 + i;
        C[(size_t)row * N + col] = (acc[m][n][i] + bv);
      }
    }
  }
}

// ---------------- MFMA flash attention, swapped-operand (S^T / O^T) ----------------
// Grid (16, 16, 4) = (pair, head, batch); 256 threads = 4 waves; butterfly pairing.
// Q/K read from fused QKV buffer (stride 1536); V from pre-transposed VbT.
// s_setprio(1) wraps the MFMA clusters (T5).
__global__ __launch_bounds__(256) void attn_k(const bf16* __restrict__ QKVg,
                                              const bf16* __restrict__ VTg,
                                              bf16* __restrict__ Og) {
  const int jp = blockIdx.x;  // pair index 0..15
  const int h = blockIdx.y;
  const int b = blockIdx.z;
  const int kv = h >> 2;  // G = 4
  const int tid = threadIdx.x;
  const int wave = tid >> 6;
  const int lane = tid & 63;
  const int fr = lane & 15;   // q (col) index within the wave's 16 q-rows
  const int quad = lane >> 4;

  __shared__ bf16 Ks[64][72];  // [key][d]     9216 B
  __shared__ bf16 Vt[64][72];  // [d][key]     9216 B
  __shared__ bf16 Pt[64][72];  // [q][key] P^T 9216 B -> 27648 total

  // staging maps
  const int skey = tid & 63;        // K: key row
  const int sdc = (tid >> 6) * 16;  // K: dim seg
  const int svd = tid >> 2;         // V: d row 0..63
  const int svk = (tid & 3) * 16;   // V: key seg
  const bf16* kbase = QKVg + (size_t)(b * T_ + skey) * QKVS_ + 1024 + kv * 64 + sdc;
  const bf16* vbase = VTg + (size_t)((b * KV_ + kv) * D_ + svd) * T_ + svk;

  for (int ph = 0; ph < 2; ++ph) {
    const int qb = ph ? (31 - jp) : jp;

    // Q fragments (B-operand layout: col=fr, k=d=quad*8+j), stride 1536.
    bf16x8 qa0, qa1;
    {
      const bf16* qsrc = QKVg + (size_t)(b * T_ + qb * 64 + wave * 16 + fr) * QKVS_ + h * 64 + quad * 8;
      qa0 = *(const bf16x8*)(qsrc);
      qa1 = *(const bf16x8*)(qsrc + 32);
    }

    f32x4 Oacc[4] = {};  // O^T: row d = dt*16+quad*4+i, col q = fr
    float m_run = MASK_NEG, l_run = 0.f;

    bf16x8 k0p, k1p, v0p, v1p;  // prefetch registers (static names)
    k0p = *(const bf16x8*)(kbase);
    k1p = *(const bf16x8*)(kbase + 8);
    v0p = *(const bf16x8*)(vbase);
    v1p = *(const bf16x8*)(vbase + 8);

    for (int kb = 0; kb <= qb; ++kb) {
      // ---- staged regs -> LDS (vmcnt of prefetch drains here) ----
      *(bf16x8*)(&Ks[skey][sdc]) = k0p;
      *(bf16x8*)(&Ks[skey][sdc + 8]) = k1p;
      *(bf16x8*)(&Vt[svd][svk]) = v0p;
      *(bf16x8*)(&Vt[svd][svk + 8]) = v1p;
      __syncthreads();

      if (kb < qb) {  // prefetch next tile; latency hidden behind compute
        const bf16* kp = kbase + (size_t)(kb + 1) * 64 * QKVS_;
        const bf16* vp = vbase + (size_t)(kb + 1) * 64;
        k0p = *(const bf16x8*)(kp);
        k1p = *(const bf16x8*)(kp + 8);
        v0p = *(const bf16x8*)(vp);
        v1p = *(const bf16x8*)(vp + 8);
      } else if (ph == 0) {  // prime next phase's tile 0 (L2-hot)
        k0p = *(const bf16x8*)(kbase);
        k1p = *(const bf16x8*)(kbase + 8);
        v0p = *(const bf16x8*)(vbase);
        v1p = *(const bf16x8*)(vbase + 8);
      }

      // ---- S^T = K·Q^T: A = K[key][d], B = Q regs ----
      f32x4 S[4] = {};
      __builtin_amdgcn_s_setprio(1);
#pragma unroll
      for (int nt = 0; nt < 4; ++nt) {
        bf16x8 kf0 = *(const bf16x8*)(&Ks[nt * 16 + fr][quad * 8]);
        bf16x8 kf1 = *(const bf16x8*)(&Ks[nt * 16 + fr][32 + quad * 8]);
        S[nt] = __builtin_amdgcn_mfma_f32_16x16x32_bf16(kf0, qa0, S[nt], 0, 0, 0);
        S[nt] = __builtin_amdgcn_mfma_f32_16x16x32_bf16(kf1, qa1, S[nt], 0, 0, 0);
      }
      __builtin_amdgcn_s_setprio(0);

      if (kb == qb) {  // causal mask, diagonal block only: key_local > q_local
        const int ql = wave * 16 + fr;
#pragma unroll
        for (int nt = 0; nt < 4; ++nt)
#pragma unroll
          for (int i = 0; i < 4; ++i)
            if (nt * 16 + quad * 4 + i > ql) S[nt][i] = MASK_NEG;
      }

      // ---- online softmax (base-2 domain); one q per lane ----
      float pm = S[0][0];
#pragma unroll
      for (int nt = 0; nt < 4; ++nt)
#pragma unroll
        for (int i = 0; i < 4; ++i) pm = fmaxf(pm, S[nt][i]);
      pm = fmaxf(pm, __shfl_xor(pm, 16, 64));
      pm = fmaxf(pm, __shfl_xor(pm, 32, 64));
      if (pm > m_run) {  // exact defer: skip O-rescale when max doesn't grow
        float al = exp2f(m_run - pm);
        m_run = pm;
        l_run *= al;
#pragma unroll
        for (int dt = 0; dt < 4; ++dt)
#pragma unroll
          for (int i = 0; i < 4; ++i) Oacc[dt][i] *= al;
      }
      float ps = 0.f;
#pragma unroll
      for (int nt = 0; nt < 4; ++nt)
#pragma unroll
        for (int i = 0; i < 4; ++i) {
          float p = exp2f(S[nt][i] - m_run);  // arg <= 0
          S[nt][i] = p;
          ps += p;
        }
      ps += __shfl_xor(ps, 16, 64);
      ps += __shfl_xor(ps, 32, 64);
      l_run += ps;

      // ---- P^T -> LDS: lane's 4 keys per nt are contiguous -> b64 writes ----
#pragma unroll
      for (int nt = 0; nt < 4; ++nt) {
        bf16x4 w;
#pragma unroll
        for (int i = 0; i < 4; ++i) w[i] = (bf16)S[nt][i];
        *(bf16x4*)(&Pt[wave * 16 + fr][nt * 16 + quad * 4]) = w;
      }
      __threadfence_block();  // drain ds_write before same-wave ds_read

      // ---- O^T += V^T·P^T: A = V^T[d][key], B = P^T[key][q] ----
      bf16x8 pb0 = *(const bf16x8*)(&Pt[wave * 16 + fr][quad * 8]);
      bf16x8 pb1 = *(const bf16x8*)(&Pt[wave * 16 + fr][32 + quad * 8]);
      __builtin_amdgcn_s_setprio(1);
#pragma unroll
      for (int dt = 0; dt < 4; ++dt) {
        bf16x8 vf0 = *(const bf16x8*)(&Vt[dt * 16 + fr][quad * 8]);
        bf16x8 vf1 = *(const bf16x8*)(&Vt[dt * 16 + fr][32 + quad * 8]);
        Oacc[dt] = __builtin_amdgcn_mfma_f32_16x16x32_bf16(vf0, pb0, Oacc[dt], 0, 0, 0);
        Oacc[dt] = __builtin_amdgcn_mfma_f32_16x16x32_bf16(vf1, pb1, Oacc[dt], 0, 0, 0);
      }
      __builtin_amdgcn_s_setprio(0);
      __syncthreads();  // all LDS reads done before next iter's staging writes
    }

    // ---- epilogue: O^T holds 16 d-values for q = fr; pack 4x b64 stores ----
    {
      float inv = 1.f / fmaxf(l_run, 1e-30f);
      bf16* dst = Og + (size_t)(b * T_ + qb * 64 + wave * 16 + fr) * E_ + h * 64;
#pragma unroll
      for (int dt = 0; dt < 4; ++dt) {
        bf16x4 o;
#pragma unroll
        for (int i = 0; i < 4; ++i) o[i] = (bf16)(Oacc[dt][i] * inv);
        *(bf16x4*)(dst + dt * 16 + quad * 4) = o;
      }
    }
  }
}

extern "C" void kernel_launch(void* const* d_in, const int* in_sizes, int n_in,
                              void* d_out, int out_size, void* d_ws, size_t ws_size,
                              hipStream_t stream) {
  (void)in_sizes; (void)n_in; (void)out_size; (void)ws_size;
  // Reference dtypes are float32 for ALL inputs and the output.
  const float* hidden = (const float*)d_in[0];
  // d_in[1] = attention_mask: deterministically causal -> applied analytically
  const float* Wq = (const float*)d_in[2];
  const float* bq = (const float*)d_in[3];
  const float* Wk = (const float*)d_in[4];
  const float* bk = (const float*)d_in[5];
  const float* Wv = (const float*)d_in[6];
  const float* bv = (const float*)d_in[7];
  const float* Wo = (const float*)d_in[8];
  const float* bo = (const float*)d_in[9];
  float* out = (float*)d_out;

  char* ws = (char*)d_ws;
  bf16* WqkvT = (bf16*)(ws);                  // [0, 3 MB)   1536x1024 bf16
  bf16* WoT   = (bf16*)(ws + (3u << 20));     // [3, 5 MB)   1024x1024 bf16
  bf16* QKVb  = (bf16*)(ws + (5u << 20));     // [5, 29 MB)  8192x1536 bf16
  // Hb (bf16 hidden) aliases Ab: Hb used only before attn_k, Ab only from attn_k on.
  bf16* Hb    = (bf16*)(ws + (29u << 20));    // [29, 45 MB)
  bf16* Ab    = (bf16*)(ws + (29u << 20));
  bf16* VbT   = (bf16*)(ws + (45u << 20));    // [45, 49 MB)

  cast_k<<<dim3(M_ * E_ / (256 * 8)), 256, 0, stream>>>(hidden, Hb);
  wprep_k<<<dim3(32, 32, 4), 256, 0, stream>>>(Wq, Wk, Wv, Wo, WqkvT, WoT);

  // fused QKV projection: Q scaled by D^-0.5*log2(e); K/V unscaled
  qkv_gemm_k<<<dim3(64, 12), 256, 0, stream>>>(Hb, WqkvT, bq, bk, bv, QKVb);

  vtrans_k<<<dim3(256, 8), 256, 0, stream>>>(QKVb, VbT);

  attn_k<<<dim3(16, 16, 4), 256, 0, stream>>>(QKVb, VbT, Ab);

  gemm128_k<<<dim3(64, 8), 256, 0, stream>>>(Ab, WoT, bo, out, M_, E_, E_);
}